// Round 4
// baseline (819.729 us; speedup 1.0000x reference)
//
#include <hip/hip_runtime.h>
#include <cstdint>
#include <cstddef>

// ---------------------------------------------------------------------------
// AlphaNet: features -> BN -> conv(1x3,16) -> relu -> fc1(43200->512) -> relu
//          -> fc2(512->128) -> sigmoid -> fc3(128->1)
// fc1 = f16 MFMA GEMM (A scaled 2^-8), split-K=15, atomic fp32 reduce.
// R4: operands pre-stored in MFMA FRAGMENT order -> barrier-free LDS-free
//     GEMM K-loop (register double-buffered global_load_dwordx4 -> MFMA).
// Fragment unit layout per (tile,it): [g(8)][h(2)][lane(64) x 16B],
//   lane = quad*16 + m16 holds X[g*16 + m16][h*32 + quad*8 + j], j=0..7.
// ---------------------------------------------------------------------------

typedef _Float16 f16;
typedef f16 f16x8 __attribute__((ext_vector_type(8)));
typedef float f32x4 __attribute__((ext_vector_type(4)));

#define CHUNK    2048              // samples per pipeline pass (2 passes)
#define K_FC1    43200             // 16*270*10
#define IT_TOT   675               // K_FC1 / 64
#define SPLITK   15
#define IT_BLK   45                // 675 / 15
#define MT_CHUNK 16                // 2048 / 128
#define TILE_ELEMS 8192            // 128*64 f16 per (tile,it) block

__device__ __forceinline__ float fillv(float x) { return isfinite(x) ? x : 0.0f; }

// ---------------------------------------------------------------------------
// Kernel 1: fc1_w fp32 -> f16, retiled to fragment order.
// One block per (nt,it) = 2700 blocks.
// ---------------------------------------------------------------------------
__global__ __launch_bounds__(256) void retile_w(const float* __restrict__ w,
                                                f16* __restrict__ Wt) {
    const int bid = blockIdx.x;               // nt*675 + it
    const int nt = bid / 675, it = bid % 675;
    const int t = threadIdx.x;
    f16* dst = Wt + (size_t)bid * TILE_ELEMS;
    #pragma unroll
    for (int j = 0; j < 4; ++j) {
        int t2 = t + 256 * j;                 // 0..1023 16B units
        int r = t2 >> 3, u = t2 & 7;          // row, k-octet
        int h = u >> 2, q = u & 3;
        int g = r >> 4, m16 = r & 15;
        const float* s = w + (size_t)(nt * 128 + r) * K_FC1 + it * 64 + u * 8;
        float4 a = *(const float4*)s;
        float4 b = *(const float4*)(s + 4);
        f16x8 o = { (f16)a.x, (f16)a.y, (f16)a.z, (f16)a.w,
                    (f16)b.x, (f16)b.y, (f16)b.z, (f16)b.w };
        *(f16x8*)(dst + g * 1024 + h * 512 + q * 128 + m16 * 8) = o;
    }
}

// ---------------------------------------------------------------------------
// Kernel 2: per-sample features + BN + conv + relu -> A16 fragment order
// (scaled 2^-8). One block per sample, 256 threads.
// Feature rows: corr 0-104 | cov 105-209 | std 210-224 | zs 225-239
//               | ret 240-254 | dl 255-269 ; 12 windows each.
// ---------------------------------------------------------------------------
__global__ __launch_bounds__(256) void stage_a(
    const float* __restrict__ data, const float* __restrict__ bn_g,
    const float* __restrict__ bn_b, const float* __restrict__ bn_m,
    const float* __restrict__ bn_v, const float* __restrict__ conv_w,
    const float* __restrict__ conv_b, f16* __restrict__ A16, int n0)
{
    __shared__ float raw[1800];        // raw window data, becomes spread
    __shared__ float feat[270 * 12];
    __shared__ float cw[48];
    __shared__ float cb[16];
    __shared__ int   pi[105], pj[105];

    const int t = threadIdx.x;
    const int n = n0 + blockIdx.x;
    const float4* src4 = (const float4*)(data + (size_t)n * 1800);
    for (int i = t; i < 450; i += 256) ((float4*)raw)[i] = src4[i];
    if (t < 48)  cw[t] = conv_w[t];
    if (t < 16)  cb[t] = conv_b[t];
    if (t < 105) {                               // triu_indices(15, k=1) order
        int i = 0, rem = t;
        while (rem >= 14 - i) { rem -= 14 - i; ++i; }
        pi[t] = i; pj[t] = i + 1 + rem;
    }
    __syncthreads();

    // per-(f,w) stats; overwrite raw with spread
    if (t < 180) {
        int f = t / 12, w = t % 12;
        int base = f * 120 + w * 10;
        float x[10];
        #pragma unroll
        for (int s = 0; s < 10; ++s) x[s] = raw[base + s];
        float sum = 0.f;
        #pragma unroll
        for (int s = 0; s < 10; ++s) sum += x[s];
        float mean = sum * 0.1f;
        float ret = x[9] / x[0] - 1.0f;
        float dl = 0.f;
        #pragma unroll
        for (int s = 0; s < 10; ++s) dl += x[s] * ((float)(s + 1) * (1.0f / 55.0f));
        float var = 0.f;
        #pragma unroll
        for (int s = 0; s < 10; ++s) { float d = x[s] - mean; raw[base + s] = d; var += d * d; }
        var *= (1.0f / 9.0f);                    // unbiased
        float sd = sqrtf(var);
        feat[(210 + f) * 12 + w] = fillv(sd);
        feat[(225 + f) * 12 + w] = fillv(mean / sd);
        feat[(240 + f) * 12 + w] = fillv(ret);
        feat[(255 + f) * 12 + w] = fillv(dl);
    }
    __syncthreads();

    // pairwise cov / corr
    for (int q = t; q < 1260; q += 256) {
        int p = q / 12, w = q % 12;
        int i = pi[p], j = pj[p];
        int bi = i * 120 + w * 10, bj = j * 120 + w * 10;
        float cv = 0.f;
        #pragma unroll
        for (int s = 0; s < 10; ++s) cv += raw[bi + s] * raw[bj + s];
        cv *= (1.0f / 9.0f);
        float si = feat[(210 + i) * 12 + w], sj = feat[(210 + j) * 12 + w];
        feat[p * 12 + w]         = fillv(cv / (si * sj) * 0.9f);  // *(S-1)/S
        feat[(105 + p) * 12 + w] = fillv(cv);
    }
    __syncthreads();

    // BatchNorm (eval, C=1 scalar)
    float a  = bn_g[0] * rsqrtf(bn_v[0] + 1e-5f);
    float bb = bn_b[0] - bn_m[0] * a;
    for (int i = t; i < 3240; i += 256) feat[i] = feat[i] * a + bb;
    __syncthreads();

    // conv(1x3) + bias + relu -> scale 2^-8 -> clamp -> f16 -> fragment order
    const int s_idx = blockIdx.x;                // sample within chunk
    const int mt = s_idx >> 7, r = s_idx & 127;
    const int g = r >> 4, m16s = r & 15;
    f16* base = A16 + (size_t)mt * IT_TOT * TILE_ELEMS + g * 1024 + m16s * 8;
    for (int v = t; v < K_FC1 / 8; v += 256) {   // 5400 16B units
        int idx0 = v * 8;
        f16x8 ov;
        #pragma unroll
        for (int e = 0; e < 8; ++e) {
            int idx = idx0 + e;
            int oc = idx / 2700;
            int rem = idx - oc * 2700;
            int h = rem / 10;
            int wo = rem - h * 10;
            const float* fr = feat + h * 12 + wo;
            float y = cb[oc] + cw[oc * 3] * fr[0] + cw[oc * 3 + 1] * fr[1] + cw[oc * 3 + 2] * fr[2];
            y = y > 0.f ? y : 0.f;
            y *= 0.00390625f;                    // 2^-8 (exact)
            y = y < 65000.f ? y : 65000.f;       // fp16-overflow backstop
            ov[e] = (f16)y;
        }
        int it = v >> 3, h = (v >> 2) & 1, q = v & 3;
        *(f16x8*)(base + (size_t)it * TILE_ELEMS + h * 512 + q * 128) = ov;
    }
}

// ---------------------------------------------------------------------------
// Kernel 3: fc1 GEMM  Ysum[CHUNK,512] (+)= A * W^T (f16 MFMA)
// Barrier-free, LDS-free: fragments loaded straight from global (frag-order
// layout), register double-buffered. 128x128 tile, BK=64, split-K=15.
// XCD swizzle: xcd=bid&7 pins mt-pair per XCD; nt fastest so the 4 blocks
// sharing an A-tile are temporally adjacent on one XCD (L2 dedup).
// ---------------------------------------------------------------------------
__global__ __launch_bounds__(256, 2) void gemm_fc1(const f16* __restrict__ A,
                                                   const f16* __restrict__ W,
                                                   float* __restrict__ Ysum)
{
    const int bid = blockIdx.x;                   // 960 blocks
    const int xcd = bid & 7, slot = bid >> 3;     // slot 0..119
    const int nt = slot & 3;
    const int m2 = (slot >> 2) & 1;
    const int sk = slot >> 3;                     // 0..14
    const int mt = xcd * 2 + m2;

    const int tid = threadIdx.x;
    const int wave = tid >> 6, lane = tid & 63;
    const int quad = lane >> 4, m16 = lane & 15;
    const int wm = (wave & 1) << 6, wn = (wave >> 1) << 6;
    const int ga = wm >> 4, gb = wn >> 4;         // 0 or 4

    const f16* Ab = A + (size_t)(mt * IT_TOT + sk * IT_BLK) * TILE_ELEMS + lane * 8;
    const f16* Bb = W + (size_t)(nt * IT_TOT + sk * IT_BLK) * TILE_ELEMS + lane * 8;

    f16x8 a[2][2][4], b[2][2][4];                 // [buf][h][i]
    f32x4 acc[4][4] = {};

#define LOADF(B, IT) do {                                                     \
    const f16* Ap = Ab + (size_t)(IT) * TILE_ELEMS;                           \
    const f16* Bp = Bb + (size_t)(IT) * TILE_ELEMS;                           \
    _Pragma("unroll") for (int h_ = 0; h_ < 2; ++h_)                          \
    _Pragma("unroll") for (int i_ = 0; i_ < 4; ++i_) {                        \
        a[B][h_][i_] = *(const f16x8*)(Ap + ((ga + i_) * 2 + h_) * 512);      \
        b[B][h_][i_] = *(const f16x8*)(Bp + ((gb + i_) * 2 + h_) * 512);      \
    } } while (0)

#define MFMAF(B) do {                                                         \
    _Pragma("unroll") for (int h_ = 0; h_ < 2; ++h_)                          \
    _Pragma("unroll") for (int i_ = 0; i_ < 4; ++i_)                          \
    _Pragma("unroll") for (int j_ = 0; j_ < 4; ++j_)                          \
        acc[i_][j_] = __builtin_amdgcn_mfma_f32_16x16x32_f16(                 \
            a[B][h_][i_], b[B][h_][j_], acc[i_][j_], 0, 0, 0);                \
    } while (0)

    LOADF(0, 0);
    int it = 1;
    #pragma unroll 1
    for (int k2 = 0; k2 < (IT_BLK - 1) / 2; ++k2) {   // 22 double-steps
        LOADF(1, it);
        MFMAF(0);
        LOADF(0, it + 1);
        MFMAF(1);
        it += 2;
    }
    MFMAF(0);                                     // it = 44 (in buf0)

#undef LOADF
#undef MFMAF

    // C/D layout: col = lane&15, row = quad*4 + reg. Atomic split-K reduce.
    float* Yb = Ysum + (size_t)(mt * 128) * 512 + nt * 128;
    #pragma unroll
    for (int i = 0; i < 4; ++i)
        #pragma unroll
        for (int j = 0; j < 4; ++j)
            #pragma unroll
            for (int r = 0; r < 4; ++r) {
                int row = wm + i * 16 + quad * 4 + r;
                int col = wn + j * 16 + m16;
                unsafeAtomicAdd(&Yb[(size_t)row * 512 + col], acc[i][j][r]);
            }
}

// ---------------------------------------------------------------------------
// Kernel 4: head = (relu(sum*256+b1)) -> fc2 + sigmoid -> fc3
// 8 samples/block, 128 threads -> 256 blocks per chunk.
// ---------------------------------------------------------------------------
__global__ __launch_bounds__(128) void head_fc23(const float* __restrict__ y1s,
                                                 const float* __restrict__ b1,
                                                 const float* __restrict__ w2,
                                                 const float* __restrict__ b2,
                                                 const float* __restrict__ w3,
                                                 const float* __restrict__ b3,
                                                 float* __restrict__ out, int n0)
{
    __shared__ float Ys[8 * 512];    // 16 KB
    __shared__ float Y2[8 * 128];    // 4 KB
    const int t = threadIdx.x;
    const float4* yb = (const float4*)(y1s + (size_t)blockIdx.x * 8 * 512);
    const float4* b1v = (const float4*)b1;
    for (int i = t; i < 8 * 128; i += 128) {
        float4 s = yb[i];
        float4 bv = b1v[i & 127];
        float4 y;
        y.x = fmaxf(fmaf(s.x, 256.f, bv.x), 0.f);
        y.y = fmaxf(fmaf(s.y, 256.f, bv.y), 0.f);
        y.z = fmaxf(fmaf(s.z, 256.f, bv.z), 0.f);
        y.w = fmaxf(fmaf(s.w, 256.f, bv.w), 0.f);
        ((float4*)Ys)[i] = y;
    }
    __syncthreads();

    float acc[8];
    float bk = b2[t];
    #pragma unroll
    for (int s = 0; s < 8; ++s) acc[s] = bk;
    const float4* wr = (const float4*)(w2 + (size_t)t * 512);
    for (int jc = 0; jc < 128; ++jc) {
        float4 w4 = wr[jc];
        #pragma unroll
        for (int s = 0; s < 8; ++s) {
            float4 y4 = *(const float4*)(Ys + s * 512 + jc * 4);
            acc[s] += w4.x * y4.x + w4.y * y4.y + w4.z * y4.z + w4.w * y4.w;
        }
    }
    #pragma unroll
    for (int s = 0; s < 8; ++s) Y2[s * 128 + t] = 1.0f / (1.0f + expf(-acc[s]));
    __syncthreads();

    if (t < 8) {
        float sm = b3[0];
        #pragma unroll 4
        for (int k = 0; k < 128; ++k) sm += Y2[t * 128 + k] * w3[k];
        out[n0 + blockIdx.x * 8 + t] = sm;
    }
}

// ---------------------------------------------------------------------------
extern "C" void kernel_launch(void* const* d_in, const int* in_sizes, int n_in,
                              void* d_out, int out_size, void* d_ws, size_t ws_size,
                              hipStream_t stream)
{
    const float* data = (const float*)d_in[0];
    const float* bn_g = (const float*)d_in[1];
    const float* bn_b = (const float*)d_in[2];
    const float* bn_m = (const float*)d_in[3];
    const float* bn_v = (const float*)d_in[4];
    const float* cw   = (const float*)d_in[5];
    const float* cb   = (const float*)d_in[6];
    const float* fc1w = (const float*)d_in[7];
    const float* fc1b = (const float*)d_in[8];
    const float* fc2w = (const float*)d_in[9];
    const float* fc2b = (const float*)d_in[10];
    const float* fc3w = (const float*)d_in[11];
    const float* fc3b = (const float*)d_in[12];
    float* out = (float*)d_out;

    // workspace layout (total ~225.6 MB, known-safe)
    const size_t A16_BYTES = (size_t)CHUNK * K_FC1 * 2;       // 176,947,200
    const size_t W16_BYTES = (size_t)512 * K_FC1 * 2;         //  44,236,800
    const size_t Y1_BYTES  = (size_t)CHUNK * 512 * 4;         //   4,194,304
    if (ws_size < A16_BYTES + W16_BYTES + Y1_BYTES) return;

    char* ws = (char*)d_ws;
    f16*   A16 = (f16*)ws;
    f16*   W16 = (f16*)(ws + A16_BYTES);
    float* y1s = (float*)(ws + A16_BYTES + W16_BYTES);

    retile_w<<<4 * IT_TOT, 256, 0, stream>>>(fc1w, W16);

    for (int c = 0; c < 2; ++c) {
        int n0 = c * CHUNK;
        hipMemsetAsync(y1s, 0, Y1_BYTES, stream);
        stage_a<<<CHUNK, 256, 0, stream>>>(data, bn_g, bn_b, bn_m, bn_v, cw, cb, A16, n0);
        gemm_fc1<<<8 * 120, 256, 0, stream>>>(A16, W16, y1s);
        head_fc23<<<CHUNK / 8, 128, 0, stream>>>(y1s, fc1b, fc2w, fc2b, fc3w, fc3b, out, n0);
    }
}